// Round 7
// baseline (122.449 us; speedup 1.0000x reference)
//
#include <hip/hip_runtime.h>
#include <math.h>

#define NCOLS 5000
#define NF4   1250            // NCOLS / 4
#define QF4   313             // quarters 0-2: 313 float4; quarter 3: 311
#define BLOCK 256
#define NWAVES 4
#define TOPKK 10
#define TR    3               // threshold rounds/wave (4*3 >= 12 >= k)
#define CAP   64              // quarter candidate capacity (expect ~15-40)
#define OUTK  16              // top-k output slots per quarter per path

// ws layout (nrq = nrows*4):
//   sums : [nrq][8]  (nv, sq, sp, seyy, seyu, aspu, aspd, 0)
//   top  : [nrq][OUTK] float2 (key bits, u value), zero-padded
//   bot  : [nrq][OUTK] float2 (key bits, d value), zero-padded

__device__ __forceinline__ unsigned mono_f32(float f) {
  unsigned u = __float_as_uint(f);
  return (u & 0x80000000u) ? ~u : (u | 0x80000000u);
}
__device__ __forceinline__ float wave_sum_f(float v) {
#pragma unroll
  for (int o = 1; o < 64; o <<= 1) v += __shfl_xor(v, o);
  return v;
}
__device__ __forceinline__ int wave_sum_i(int v) {
#pragma unroll
  for (int o = 1; o < 64; o <<= 1) v += __shfl_xor(v, o);
  return v;
}
__device__ __forceinline__ unsigned wave_max_u(unsigned v) {
#pragma unroll
  for (int o = 1; o < 64; o <<= 1) {
    unsigned w = __shfl_xor(v, o);
    v = w > v ? w : v;
  }
  return v;
}
__device__ __forceinline__ void gl_lds16(const float4* g, float4* l) {
  __builtin_amdgcn_global_load_lds(
      (const __attribute__((address_space(1))) void*)(g),
      (__attribute__((address_space(3))) void*)(l), 16, 0, 0);
}

// ============================ PASS 1 =====================================
// 4 blocks per row (quarters). DMA-to-LDS staging (no payload VGPRs ->
// fits the 64-VGPR cap of (256,8) -> 8 blocks/CU = 32 waves/CU; serial
// tails overlap across resident blocks). Emits per-quarter sums + exact
// top-16 / bottom-16 (key,value) pairs.
extern "C" __global__ __launch_bounds__(BLOCK, 8)
void part_kernel(const float* __restrict__ up, const float* __restrict__ down,
                 const float* __restrict__ yt, const int* __restrict__ masks,
                 float* __restrict__ ws_sums, float2* __restrict__ ws_top,
                 float2* __restrict__ ws_bot) {
  __shared__ float4 y_s[320], u_s[320], d_s[320];   // 15360 B
  __shared__ float red_f[7][NWAVES];
  __shared__ unsigned t1w_t[NWAVES], t1w_b[NWAVES];
  __shared__ unsigned keys_t[CAP]; __shared__ int col_t[CAP];
  __shared__ unsigned keys_b[CAP]; __shared__ int col_b[CAP];
  __shared__ int ct, cb;

  const int tid = threadIdx.x;
  const int lane = tid & 63;
  const int wv = tid >> 6;
  const int bq = blockIdx.x;
  const int row = bq >> 2;
  const int q = bq & 3;
  const int qlen = (q == 3) ? (NF4 - 3 * QF4) : QF4;   // 311 or 313
  const long long b4 = (long long)row * NF4 + q * QF4;

  if (tid == 0) { ct = 0; cb = 0; }

  const float4* yt4q = (const float4*)yt + b4;
  const float4* up4q = (const float4*)up + b4;
  const float4* dn4q = (const float4*)down + b4;
  const int4*   mk4q = (const int4*)masks + b4;

  // Masks first (register loads; compiler auto-waits at first use).
  const int4 mA = mk4q[tid];                        // tid < 256 <= 311: in-bounds
  int4 mB = make_int4(0, 0, 0, 0);
  if (wv == 0) mB = mk4q[(256 + tid < qlen) ? (256 + tid) : (qlen - 1)];
  __builtin_amdgcn_sched_barrier(0);

  // DMA: each wave stages the section it consumes. Chunk B (elements
  // 256..qlen) is consumed only by wave 0 (qlen-256 <= 57 <= 64 lanes).
  {
    const int wb = wv * 64;
    gl_lds16(yt4q + wb + lane, y_s + wb);
    gl_lds16(up4q + wb + lane, u_s + wb);
    gl_lds16(dn4q + wb + lane, d_s + wb);
    if (wv == 0) {
      const int fB = (256 + lane < qlen) ? (256 + lane) : (qlen - 1);
      gl_lds16(yt4q + fB, y_s + 256);
      gl_lds16(up4q + fB, u_s + 256);
      gl_lds16(dn4q + fB, d_s + 256);
    }
  }
  __builtin_amdgcn_sched_barrier(0);

  int vmask = 0;
  float sq = 0.f, sp = 0.f, seyy = 0.f, seyu = 0.f;
  float pu = 1.f, pd = 1.f;                 // softplus group-products
  unsigned tmax = 0u, tbmax = 0u;

  // Grouped softplus: pu *= (1+e^u) per valid elem; ONE log per thread per
  // path after the loop (trans/elem 5 -> ~3.25). Product of <=8 factors,
  // each <= 1+e^|u|max: fp32-safe to |u| ~ 20 (inputs ~N(0,1)).
#define ELEM(bit, Y, U, D, M, INB)                                      \
  {                                                                     \
    const bool valid = (INB) && ((M) > 0);                              \
    const float y = (Y), u = (U), d = (D);                              \
    const unsigned kd = valid ? mono_f32(y) : 0u;                       \
    const unsigned kb2 = valid ? ~kd : 0u;                              \
    vmask |= valid ? (1 << (bit)) : 0;                                  \
    tmax = kd > tmax ? kd : tmax;                                       \
    tbmax = kb2 > tbmax ? kb2 : tbmax;                                  \
    const float mf = valid ? 1.f : 0.f;                                 \
    const float ey = __expf(y);                                         \
    const float eu = __expf(u);                                         \
    const float ed = __expf(d);                                         \
    const float mey = mf * ey;                                          \
    sq += mey;                                                          \
    seyy = fmaf(mey, y, seyy);                                          \
    seyu = fmaf(mey, u, seyu);                                          \
    sp += mf * eu;                                                      \
    pu *= valid ? (1.f + eu) : 1.f;                                     \
    pd *= valid ? (1.f + ed) : 1.f;                                     \
  }

#define CHUNKA()                                                        \
  {                                                                     \
    const float4 yv = y_s[tid];                                         \
    const float4 uv = u_s[tid];                                         \
    const float4 dv = d_s[tid];                                         \
    ELEM(0, yv.x, uv.x, dv.x, mA.x, true)                               \
    ELEM(1, yv.y, uv.y, dv.y, mA.y, true)                               \
    ELEM(2, yv.z, uv.z, dv.z, mA.z, true)                               \
    ELEM(3, yv.w, uv.w, dv.w, mA.w, true)                               \
  }
#define CHUNKB()                                                        \
  {                                                                     \
    const bool inbB = (256 + tid) < qlen;                               \
    const float4 yv = y_s[256 + tid];                                   \
    const float4 uv = u_s[256 + tid];                                   \
    const float4 dv = d_s[256 + tid];                                   \
    ELEM(4, yv.x, uv.x, dv.x, mB.x, inbB)                               \
    ELEM(5, yv.y, uv.y, dv.y, mB.y, inbB)                               \
    ELEM(6, yv.z, uv.z, dv.z, mB.z, inbB)                               \
    ELEM(7, yv.w, uv.w, dv.w, mB.w, inbB)                               \
  }

  if (wv == 0) {
    asm volatile("s_waitcnt vmcnt(3)" ::: "memory");   // A ready, B in flight
    __builtin_amdgcn_sched_barrier(0);
    CHUNKA()
    asm volatile("s_waitcnt vmcnt(0)" ::: "memory");
    __builtin_amdgcn_sched_barrier(0);
    CHUNKB()
  } else {
    asm volatile("s_waitcnt vmcnt(0)" ::: "memory");
    __builtin_amdgcn_sched_barrier(0);
    CHUNKA()
  }
#undef CHUNKA
#undef CHUNKB
#undef ELEM

  const float aspu = __logf(pu);
  const float aspd = __logf(pd);

  int nv_l = wave_sum_i(__popc((unsigned)vmask));
  sq = wave_sum_f(sq);
  sp = wave_sum_f(sp);
  seyy = wave_sum_f(seyy);
  seyu = wave_sum_f(seyu);
  const float au = wave_sum_f(aspu);
  const float ad = wave_sum_f(aspd);

  // Per-wave TR=3 thresholds (top/bottom interleaved for ILP).
  unsigned t1t = 0u, t1b_ = 0u;
  {
    unsigned vt = tmax, vb = tbmax;
#pragma unroll
    for (int r = 0; r < TR; ++r) {
      const unsigned mt = wave_max_u(vt);
      const unsigned mb_ = wave_max_u(vb);
      if (vt == mt) vt = 0u;
      if (vb == mb_) vb = 0u;
      t1t = mt; t1b_ = mb_;
    }
  }
  if (lane == 0) {
    red_f[0][wv] = (float)nv_l;
    red_f[1][wv] = sq;  red_f[2][wv] = sp;
    red_f[3][wv] = seyy; red_f[4][wv] = seyu;
    red_f[5][wv] = au;  red_f[6][wv] = ad;
    t1w_t[wv] = t1t; t1w_b[wv] = t1b_;
  }
  __syncthreads();

  // Block threshold: min over 4 waves -> >= 12 >= k candidates survive
  // (a wave with <3 valid yields 0 -> admit all valid; see analysis).
  unsigned t1 = t1w_t[0], t1b = t1w_b[0];
#pragma unroll
  for (int w = 1; w < NWAVES; ++w) {
    t1 = t1w_t[w] < t1 ? t1w_t[w] : t1;
    t1b = t1w_b[w] < t1b ? t1w_b[w] : t1b;
  }
  const int nv_q = (int)(red_f[0][0] + red_f[0][1] + red_f[0][2] + red_f[0][3]);

  // Compact candidates (keys recomputed from LDS-resident y).
  {
    const int mbA = vmask & 0xF;
    if (mbA) {
      const float4 yv = y_s[tid];
      const float ya[4] = {yv.x, yv.y, yv.z, yv.w};
#pragma unroll
      for (int c = 0; c < 4; ++c) {
        if ((mbA >> c) & 1) {
          const unsigned kd = mono_f32(ya[c]);
          if (kd >= t1) {
            const int i = atomicAdd(&ct, 1);
            if (i < CAP) { keys_t[i] = kd; col_t[i] = (tid << 2) + c; }
          }
          const unsigned kb2 = ~kd;
          if (kb2 >= t1b) {
            const int i = atomicAdd(&cb, 1);
            if (i < CAP) { keys_b[i] = kb2; col_b[i] = (tid << 2) + c; }
          }
        }
      }
    }
    const int mbB = (vmask >> 4) & 0xF;
    if (mbB) {
      const float4 yv = y_s[256 + tid];
      const float ya[4] = {yv.x, yv.y, yv.z, yv.w};
#pragma unroll
      for (int c = 0; c < 4; ++c) {
        if ((mbB >> c) & 1) {
          const unsigned kd = mono_f32(ya[c]);
          if (kd >= t1) {
            const int i = atomicAdd(&ct, 1);
            if (i < CAP) { keys_t[i] = kd; col_t[i] = ((256 + tid) << 2) + c; }
          }
          const unsigned kb2 = ~kd;
          if (kb2 >= t1b) {
            const int i = atomicAdd(&cb, 1);
            if (i < CAP) { keys_b[i] = kb2; col_b[i] = ((256 + tid) << 2) + c; }
          }
        }
      }
    }
  }
  __syncthreads();

  // Tails in parallel across waves: wv0 = exact top-16, wv1 = bottom-16,
  // wv2 = sums store. No further barriers.
  const int kq = nv_q < TOPKK ? nv_q : TOPKK;
  if (wv == 0) {
    const int n = ct < CAP ? ct : CAP;
    const unsigned kc = (lane < n) ? keys_t[lane] : 0u;
    unsigned thr = 0u;
#pragma unroll
    for (int bb = 31; bb >= 0; --bb) {
      const unsigned t = thr | (1u << bb);
      thr = (__popcll(__ballot(kc >= t)) >= kq) ? t : thr;
    }
    const bool sel = (kc >= thr) && (kc != 0u);
    const unsigned long long msk = __ballot(sel);
    const int idx = __popcll(msk & ((1ull << lane) - 1ull));
    if (sel && idx < OUTK)
      ws_top[bq * OUTK + idx] =
          make_float2(__uint_as_float(kc), ((const float*)u_s)[col_t[lane]]);
    int cnt = __popcll(msk);
    cnt = cnt < OUTK ? cnt : OUTK;
    if (lane >= cnt && lane < OUTK)
      ws_top[bq * OUTK + lane] = make_float2(0.f, 0.f);
  } else if (wv == 1) {
    const int n = cb < CAP ? cb : CAP;
    const unsigned kc = (lane < n) ? keys_b[lane] : 0u;
    unsigned thr = 0u;
#pragma unroll
    for (int bb = 31; bb >= 0; --bb) {
      const unsigned t = thr | (1u << bb);
      thr = (__popcll(__ballot(kc >= t)) >= kq) ? t : thr;
    }
    const bool sel = (kc >= thr) && (kc != 0u);
    const unsigned long long msk = __ballot(sel);
    const int idx = __popcll(msk & ((1ull << lane) - 1ull));
    if (sel && idx < OUTK)
      ws_bot[bq * OUTK + idx] =
          make_float2(__uint_as_float(kc), ((const float*)d_s)[col_b[lane]]);
    int cnt = __popcll(msk);
    cnt = cnt < OUTK ? cnt : OUTK;
    if (lane >= cnt && lane < OUTK)
      ws_bot[bq * OUTK + lane] = make_float2(0.f, 0.f);
  } else if (wv == 2 && lane < 8) {
    const float s = (lane < 7)
        ? red_f[lane][0] + red_f[lane][1] + red_f[lane][2] + red_f[lane][3]
        : 0.f;
    ws_sums[bq * 8 + lane] = s;
  }
}

// ============================ PASS 2 =====================================
// One wave per row: fold 4 quarter sums, merge 4x16 candidates (row top-10
// is a subset), single 64-lane ballot search per path, loss.
extern "C" __global__ __launch_bounds__(256, 8)
void finish_kernel(const float* __restrict__ ws_sums,
                   const float2* __restrict__ ws_top,
                   const float2* __restrict__ ws_bot,
                   float* __restrict__ out, int nrows, float inv_nrows) {
  __shared__ float wl[NWAVES];
  const int tid = threadIdx.x;
  const int lane = tid & 63;
  const int wv = tid >> 6;
  const int row = blockIdx.x * NWAVES + wv;

  float loss = 0.f;
  if (row < nrows) {
    // lane l<32 loads (quarter=l>>3, field=l&7); xor-fold leaves S_i at lane i.
    float v = 0.f;
    if (lane < 32) v = ws_sums[(row * 4 + (lane >> 3)) * 8 + (lane & 7)];
    v += __shfl_xor(v, 8);
    v += __shfl_xor(v, 16);
    const float nvf = __shfl(v, 0);
    const int nv = (int)nvf;
    if (nv > 0) {
      const int k = nv < TOPKK ? nv : TOPKK;
      const float2 a = ws_top[row * 64 + lane];   // 4 quarters x 16 slots
      const float2 bt = ws_bot[row * 64 + lane];
      const unsigned kt = __float_as_uint(a.x);
      const unsigned kb = __float_as_uint(bt.x);
      unsigned thr_t = 0u, thr_b = 0u;
#pragma unroll
      for (int bb = 31; bb >= 0; --bb) {
        const unsigned tt = thr_t | (1u << bb);
        const unsigned tb = thr_b | (1u << bb);
        thr_t = (__popcll(__ballot(kt >= tt)) >= k) ? tt : thr_t;
        thr_b = (__popcll(__ballot(kb >= tb)) >= k) ? tb : thr_b;
      }
      const float su = wave_sum_f((kt >= thr_t && kt != 0u) ? a.y : 0.f);
      const float sd = wave_sum_f((kb >= thr_b && kb != 0u) ? bt.y : 0.f);
      const float SQ = __shfl(v, 1), SP = __shfl(v, 2);
      const float SYY = __shfl(v, 3), SYU = __shfl(v, 4);
      const float ASU = __shfl(v, 5), ASD = __shfl(v, 6);
      const float kl = (SYY - SYU) / SQ - __logf(SQ) + __logf(SP);
      loss = ((ASU - su) + 0.5f * (ASD - sd) + 0.3f * kl) / nvf;
    }
  }
  if (lane == 0) wl[wv] = loss;
  __syncthreads();
  if (tid == 0)
    atomicAdd(out, (wl[0] + wl[1] + wl[2] + wl[3]) * inv_nrows);
}

extern "C" void kernel_launch(void* const* d_in, const int* in_sizes, int n_in,
                              void* d_out, int out_size, void* d_ws, size_t ws_size,
                              hipStream_t stream) {
  const float* up_logits   = (const float*)d_in[0];
  const float* down_logits = (const float*)d_in[1];
  const float* y_true      = (const float*)d_in[2];
  const int*   masks       = (const int*)d_in[3];

  const int nrows = in_sizes[0] / NCOLS;
  const int nrq = nrows * 4;

  float* wsf = (float*)d_ws;
  float* ws_sums = wsf;                                  // nrq*8 floats
  float2* ws_top = (float2*)(wsf + (size_t)nrq * 8);     // nrq*16 float2
  float2* ws_bot = ws_top + (size_t)nrq * OUTK;          // nrq*16 float2
  (void)ws_size;

  hipMemsetAsync(d_out, 0, sizeof(float) * (size_t)out_size, stream);
  part_kernel<<<nrq, BLOCK, 0, stream>>>(up_logits, down_logits, y_true, masks,
                                         ws_sums, ws_top, ws_bot);
  finish_kernel<<<(nrows + NWAVES - 1) / NWAVES, 256, 0, stream>>>(
      ws_sums, ws_top, ws_bot, (float*)d_out, nrows, 1.0f / (float)nrows);
}